// Round 3
// baseline (74.602 us; speedup 1.0000x reference)
//
#include <hip/hip_runtime.h>

#define B_DIM 512
#define D_DIM 512
#define O_DIM 512
#define KSPLIT 8

// logits[b,o] = sum_d [ (-ic)*x^2 + (2*mu*ic)*x ] + (-sum_d mu^2*ic)
// Main: grid 512 = (ks)x(ob)x(bb); 64b x 64o x 64d per block, 256 thr (4 waves
// of 32b x 32o), 4x4 micro-tile/lane. All LDS rows padded to 17 float4s:
// conflict-free b128 reads with pure-immediate offsets (no inner-loop addr math).
// Partials -> ws; reduce kernel sums KSPLIT splits. No atomics, deterministic.

__global__ __launch_bounds__(256, 2)
void gda_main(const float* __restrict__ x,
              const float* __restrict__ mu,
              const float* __restrict__ ic,
              float* __restrict__ ws) {
    __shared__ float4 lds_x[64 * 17];         // [b][g], row stride 17
    __shared__ float4 lds_a[64 * 17];         // a' = -ic
    __shared__ float4 lds_b[64 * 17];         // b' = 2*mu*ic
    __shared__ float  lds_cp[64 * 17];        // mu^2*ic partials, padded
    __shared__ float  lds_c[64];              // -sum over this d-range

    const int tid = threadIdx.x;
    const int bid = blockIdx.x;
    const int bb = bid & 7, ob = (bid >> 3) & 7, ks = bid >> 6;
    const int b0 = bb * 64, o0 = ob * 64, d0 = ks * 64;

    // ---- stage: coalesced global loads, fused transform ----
    const int g   = tid & 15;
    const int row = tid >> 4;
#pragma unroll
    for (int i = 0; i < 4; ++i) {
        const int r = row + 16 * i;           // 0..63
        const int col = d0 + g * 4;
        const float4 xv = *(const float4*)&x [(b0 + r) * D_DIM + col];
        lds_x[r * 17 + g] = xv;
        const float4 m4 = *(const float4*)&mu[(o0 + r) * D_DIM + col];
        const float4 c4 = *(const float4*)&ic[(o0 + r) * D_DIM + col];
        float4 a4, b4;
        a4.x = -c4.x;              a4.y = -c4.y;
        a4.z = -c4.z;              a4.w = -c4.w;
        b4.x = 2.0f * m4.x * c4.x; b4.y = 2.0f * m4.y * c4.y;
        b4.z = 2.0f * m4.z * c4.z; b4.w = 2.0f * m4.w * c4.w;
        lds_a[r * 17 + g] = a4;
        lds_b[r * 17 + g] = b4;
        lds_cp[r * 17 + g] = m4.x * m4.x * c4.x + m4.y * m4.y * c4.y
                           + m4.z * m4.z * c4.z + m4.w * m4.w * c4.w;
    }
    __syncthreads();

    // per-o constant for this d-range (consumed after the 2nd barrier)
    if (tid < 64) {
        float s = 0.0f;
#pragma unroll
        for (int q = 0; q < 16; ++q) s += lds_cp[tid * 17 + q];
        lds_c[tid] = -s;
    }

    // ---- compute: 4 waves of 32b x 32o, 4x4 micro-tile per lane ----
    const int w    = tid >> 6;
    const int lane = tid & 63;
    const int cb   = lane >> 3;               // b-sub 0..7 (x reads: 8-way broadcast)
    const int r8   = lane & 7;                // o-sub 0..7 (a/b reads: 8-way broadcast)
    const int wb   = (w & 1) * 32, wo = (w >> 1) * 32;

    const float4* xb = &lds_x[(wb + cb) * 17];   // + k*136 + gg
    const float4* ap = &lds_a[(wo + r8) * 17];   // + j*136 + gg
    const float4* bp = &lds_b[(wo + r8) * 17];

    float acc[16];
#pragma unroll
    for (int q = 0; q < 16; ++q) acc[q] = 0.0f;

#pragma unroll
    for (int gg = 0; gg < 16; ++gg) {
        float4 xr[4], xs[4];
#pragma unroll
        for (int k = 0; k < 4; ++k) {
            xr[k] = xb[k * 136 + gg];         // imm-offset ds_read_b128
            xs[k].x = xr[k].x * xr[k].x;
            xs[k].y = xr[k].y * xr[k].y;
            xs[k].z = xr[k].z * xr[k].z;
            xs[k].w = xr[k].w * xr[k].w;
        }
#pragma unroll
        for (int j = 0; j < 4; ++j) {
            const float4 a4 = ap[j * 136 + gg];
            const float4 b4 = bp[j * 136 + gg];
#pragma unroll
            for (int k = 0; k < 4; ++k) {
                float t = acc[k * 4 + j];
                t = fmaf(a4.x, xs[k].x, t);  t = fmaf(b4.x, xr[k].x, t);
                t = fmaf(a4.y, xs[k].y, t);  t = fmaf(b4.y, xr[k].y, t);
                t = fmaf(a4.z, xs[k].z, t);  t = fmaf(b4.z, xr[k].z, t);
                t = fmaf(a4.w, xs[k].w, t);  t = fmaf(b4.w, xr[k].w, t);
                acc[k * 4 + j] = t;
            }
        }
    }
    __syncthreads();                          // lds_c ready

    // ---- epilogue: partials (+ per-o constant) to workspace ----
    float* wsb = ws + (size_t)bid * 4096;
#pragma unroll
    for (int j = 0; j < 4; ++j) {
        const float cc = lds_c[wo + r8 + 8 * j];
#pragma unroll
        for (int k = 0; k < 4; ++k)
            wsb[(wb + cb + 8 * k) * 64 + (wo + r8 + 8 * j)] = acc[k * 4 + j] + cc;
    }
}

__global__ __launch_bounds__(256, 4)
void gda_reduce(const float* __restrict__ ws, float* __restrict__ out) {
    const int tid = threadIdx.x;
#pragma unroll
    for (int p = 0; p < 4; ++p) {
        const int idx = blockIdx.x * 1024 + p * 256 + tid;   // float4 index
        const int b  = idx >> 7;                              // 128 float4 per b-row
        const int o4 = idx & 127;
        const int ob = o4 >> 4, ol4 = o4 & 15;
        const int bbv = b >> 6, bl = b & 63;
        const float* base = ws + ((ob * 8 + bbv) * 4096 + bl * 64 + ol4 * 4);
        float4 s = {0.0f, 0.0f, 0.0f, 0.0f};
#pragma unroll
        for (int k = 0; k < KSPLIT; ++k) {
            const float4 v = *(const float4*)(base + k * 262144);
            s.x += v.x; s.y += v.y; s.z += v.z; s.w += v.w;
        }
        ((float4*)out)[idx] = s;
    }
}

extern "C" void kernel_launch(void* const* d_in, const int* in_sizes, int n_in,
                              void* d_out, int out_size, void* d_ws, size_t ws_size,
                              hipStream_t stream) {
    const float* x  = (const float*)d_in[0];
    const float* mu = (const float*)d_in[1];
    const float* ic = (const float*)d_in[2];
    float* ws  = (float*)d_ws;
    float* out = (float*)d_out;

    gda_main  <<<dim3(512), dim3(256), 0, stream>>>(x, mu, ic, ws);
    gda_reduce<<<dim3(64),  dim3(256), 0, stream>>>(ws, out);
}